// Round 8
// baseline (339.610 us; speedup 1.0000x reference)
//
#include <hip/hip_runtime.h>
#include <cstdint>

namespace {
constexpr int kNUsers = 50000;
constexpr int kNTotal = 100000;        // N = users + items
constexpr int kD = 64;
constexpr int kHops = 3;
constexpr int kNnz = 3200000;
constexpr int kRowStride = (kHops + 1) * kD;     // 256 floats per node in embs
// packed edge word: col bits 0..16, keep bits 17..19, rowoff bits 20..26
constexpr uint32_t kColMask = (1u << 17) - 1u;
constexpr int kSBShift = 7;                      // 128 rows per super-bucket
constexpr int kSBRows = 1 << kSBShift;
constexpr int kNSB = (kNTotal + kSBRows - 1) / kSBRows;       // 782
constexpr int kSBCap = 5120;      // mean 4092, sigma 64 -> +16 sigma, fixed dataset
constexpr int kP1Batch = 2048;                   // edges per split1 block
constexpr int kP1Blocks = (kNnz + kP1Batch - 1) / kP1Batch;   // 1563
constexpr int kEPT = kP1Batch / 256;             // 8 edges per thread
}

#define ROTL32(v, r) (((v) << (r)) | ((v) >> (32 - (r))))

// JAX threefry2x32, 20 rounds — matches jax/_src/prng.py exactly.
__host__ __device__ inline void tf2x32(uint32_t k0, uint32_t k1,
                                       uint32_t &x0, uint32_t &x1) {
  const uint32_t k2 = k0 ^ k1 ^ 0x1BD11BDAu;
  x0 += k0; x1 += k1;
#define TFR(r) { x0 += x1; x1 = ROTL32(x1, r); x1 ^= x0; }
  TFR(13) TFR(15) TFR(26) TFR(6)
  x0 += k1; x1 += k2 + 1u;
  TFR(17) TFR(29) TFR(16) TFR(24)
  x0 += k2; x1 += k0 + 2u;
  TFR(13) TFR(15) TFR(26) TFR(6)
  x0 += k0; x1 += k1 + 3u;
  TFR(17) TFR(29) TFR(16) TFR(24)
  x0 += k1; x1 += k2 + 4u;
  TFR(13) TFR(15) TFR(26) TFR(6)
  x0 += k2; x1 += k0 + 5u;
#undef TFR
}

// partitionable random_bits for 32-bit draws: counter (0, i), fold x0^x1
__device__ __forceinline__ uint32_t pbits(uint32_t k0, uint32_t k1, uint32_t i) {
  uint32_t x0 = 0u, x1 = i;
  tf2x32(k0, k1, x0, x1);
  return x0 ^ x1;
}

// bits -> U[0,1) exactly like jax.random.uniform (f32): (b>>9)|0x3f800000, -1.0
__device__ __forceinline__ float u01(uint32_t b) {
  return __uint_as_float((b >> 9) | 0x3f800000u) - 1.0f;
}

// embs[:,0,:] = concat(user, item). One thread per (node, float4). Zeros tail[].
__global__ void k_init(const float* __restrict__ ue, const float* __restrict__ ie,
                       float* __restrict__ out, int* __restrict__ tail) {
  int t = blockIdx.x * blockDim.x + threadIdx.x;
  if (t < kNSB) tail[t] = 0;
  if (t >= kNTotal * 16) return;
  int n = t >> 4, c = t & 15;
  float4 v = (n < kNUsers) ? reinterpret_cast<const float4*>(ue)[n * 16 + c]
                           : reinterpret_cast<const float4*>(ie)[(n - kNUsers) * 16 + c];
  reinterpret_cast<float4*>(out)[(size_t)n * (kRowStride / 4) + c] = v;
}

// ---------------- multisplit pass 1: block-aggregated bucket append ----------------
// 1563 blocks x 2048 edges (occupancy ~55%). er cached in VGPRs between the
// histogram and write loops; er/ec/ev use non-temporal loads so the 38 MB edge
// stream doesn't evict half-assembled stage write lines from L2.
__global__ __launch_bounds__(256) void k_split1(
    const int* __restrict__ er, const int* __restrict__ ec,
    const float* __restrict__ ev, int* __restrict__ tail,
    int2* __restrict__ stage,
    uint32_t ke0_0, uint32_t ke1_0, uint32_t ke0_1, uint32_t ke1_1,
    uint32_t ke0_2, uint32_t ke1_2) {
  __shared__ int hist[kNSB];
  __shared__ int base[kNSB];
  const int t = threadIdx.x;
  const int e0 = blockIdx.x * kP1Batch;
  const int n = min(kP1Batch, kNnz - e0);
  for (int i = t; i < kNSB; i += 256) hist[i] = 0;
  __syncthreads();
  int rr[kEPT];
#pragma unroll
  for (int j = 0; j < kEPT; ++j) {
    const int i = j * 256 + t;
    rr[j] = (i < n) ? __builtin_nontemporal_load(er + e0 + i) : -1;
    if (rr[j] >= 0) atomicAdd(&hist[(uint32_t)rr[j] >> kSBShift], 1);
  }
  __syncthreads();
  for (int i = t; i < kNSB; i += 256) {
    const int c = hist[i];
    base[i] = (c > 0) ? atomicAdd(&tail[i], c) : 0;
    hist[i] = 0;                     // reuse as cursor
  }
  __syncthreads();
#pragma unroll
  for (int j = 0; j < kEPT; ++j) {
    if (rr[j] < 0) continue;
    const int e = e0 + j * 256 + t;
    const int b = (uint32_t)rr[j] >> kSBShift;
    const int pos = base[b] + atomicAdd(&hist[b], 1);
    if (pos < kSBCap) {              // 16-sigma guard; never triggers
      uint32_t x = (uint32_t)__builtin_nontemporal_load(ec + e);
      const float v = __builtin_nontemporal_load(ev + e);
      if (u01(pbits(ke0_0, ke1_0, (uint32_t)e)) >= 0.5f) x |= 1u << 17;
      if (u01(pbits(ke0_1, ke1_1, (uint32_t)e)) >= 0.5f) x |= 1u << 18;
      if (u01(pbits(ke0_2, ke1_2, (uint32_t)e)) >= 0.5f) x |= 1u << 19;
      x |= (uint32_t)(rr[j] & (kSBRows - 1)) << 20;
      stage[(size_t)b * kSBCap + pos] = make_int2((int)x, __float_as_int(v * 2.0f));
    }
  }
}

// ---------------- multisplit pass 2: per-bucket row sort (in place) ----------------
__global__ __launch_bounds__(256) void k_split2(
    const int* __restrict__ tail, int2* __restrict__ stage,
    int* __restrict__ row_start, int* __restrict__ row_len) {
  __shared__ int2 st[kSBCap];        // 40 KB
  __shared__ int lcnt[kSBRows], lsc[kSBRows], lcur[kSBRows];
  const int b = blockIdx.x;
  const int t = threadIdx.x;
  const int row0 = b << kSBShift;
  const int nrows = min(kSBRows, kNTotal - row0);
  const int n = min(tail[b], kSBCap);
  int2* reg = stage + (size_t)b * kSBCap;
  if (t < kSBRows) { lcnt[t] = 0; lcur[t] = 0; }
  for (int i = t; i < n; i += 256) st[i] = reg[i];
  __syncthreads();
  for (int i = t; i < n; i += 256)
    atomicAdd(&lcnt[((uint32_t)st[i].x >> 20) & (kSBRows - 1u)], 1);
  __syncthreads();
  if (t < kSBRows) lsc[t] = lcnt[t];
  __syncthreads();
  for (int off = 1; off < kSBRows; off <<= 1) {   // Hillis-Steele inclusive
    int add = (t >= off && t < kSBRows) ? lsc[t - off] : 0;
    __syncthreads();
    if (t < kSBRows) lsc[t] += add;
    __syncthreads();
  }
  if (t < nrows) {
    const int excl = lsc[t] - lcnt[t];
    row_start[row0 + t] = b * kSBCap + excl;
    row_len[row0 + t] = lcnt[t];
  }
  __syncthreads();
  for (int i = t; i < n; i += 256) {
    const int2 v = st[i];
    const int r = (int)(((uint32_t)v.x >> 20) & (kSBRows - 1u));
    const int pos = (lsc[r] - lcnt[r]) + atomicAdd(&lcur[r], 1);
    reg[pos] = v;
  }
}

// ---------------- fused SpMM: one wave per row ----------------
__global__ __launch_bounds__(256) void k_spmm_csr(
    const int* __restrict__ row_start, const int* __restrict__ row_len,
    const int2* __restrict__ csr,
    const float* __restrict__ src, float* __restrict__ dst,
    uint32_t hopbit, uint32_t km0, uint32_t km1) {
  __shared__ int2 stage[4][68];
  const int wave = threadIdx.x >> 6;
  const int lane = threadIdx.x & 63;
  const int r = __builtin_amdgcn_readfirstlane(blockIdx.x * 4 + wave);
  if (r >= kNTotal) return;
  const int start = row_start[r];
  const int end = start + row_len[r];
  float a0 = 0.f, a1 = 0.f, a2 = 0.f, a3 = 0.f;
  for (int base = start; base < end; base += 64) {
    const int n = min(64, end - base);
    bool keep = false;
    int2 cv = make_int2(0, 0);
    if (lane < n) {
      cv = csr[base + lane];
      keep = ((uint32_t)cv.x & hopbit) != 0u;
    }
    const uint64_t m = __ballot(keep);
    const int k = __popcll(m);
    if (keep) {
      const int slot = __popcll(m & ((1ull << lane) - 1ull));
      stage[wave][slot] = make_int2((int)((uint32_t)cv.x & kColMask), cv.y);
    }
    if (lane < 3) stage[wave][k + lane] = make_int2(0, 0);  // zero-pad for unroll tail
    for (int j = 0; j < k; j += 4) {
      const int2 e0 = stage[wave][j];
      const int2 e1 = stage[wave][j + 1];
      const int2 e2 = stage[wave][j + 2];
      const int2 e3 = stage[wave][j + 3];
      a0 += __int_as_float(e0.y) * src[(size_t)e0.x * kRowStride + lane];
      a1 += __int_as_float(e1.y) * src[(size_t)e1.x * kRowStride + lane];
      a2 += __int_as_float(e2.y) * src[(size_t)e2.x * kRowStride + lane];
      a3 += __int_as_float(e3.y) * src[(size_t)e3.x * kRowStride + lane];
    }
  }
  const float acc = (a0 + a1) + (a2 + a3);
  const float u = u01(pbits(km0, km1, (uint32_t)(r * 64 + lane)));
  dst[(size_t)r * kRowStride + lane] = (u < 0.9f) ? acc * (float)(1.0 / 0.9) : 0.0f;
}

extern "C" void kernel_launch(void* const* d_in, const int* in_sizes, int n_in,
                              void* d_out, int out_size, void* d_ws, size_t ws_size,
                              hipStream_t stream) {
  const float* ue = (const float*)d_in[0];
  const float* ie = (const float*)d_in[1];
  const float* ev = (const float*)d_in[2];
  const int*   er = (const int*)d_in[3];
  const int*   ec = (const int*)d_in[4];
  float* out = (float*)d_out;

  // keys: base = key(42) = (0,42); per hop fold_in, then partitionable split:
  // keys[j] = threefry(folded_key, (0, j)).
  uint32_t ke0[kHops], ke1[kHops], km0[kHops], km1[kHops];
  for (int hop = 0; hop < kHops; ++hop) {
    uint32_t f0 = 0u, f1 = (uint32_t)hop;
    tf2x32(0u, 42u, f0, f1);
    uint32_t e0 = 0u, e1 = 0u;
    tf2x32(f0, f1, e0, e1);
    uint32_t m0 = 0u, m1 = 1u;
    tf2x32(f0, f1, m0, m1);
    ke0[hop] = e0; ke1[hop] = e1;
    km0[hop] = m0; km1[hop] = m1;
  }

  const int BS = 256;

  // ws layout (int units):
  // row_start[100000] | row_len[100000] | tail[782] | pad | stage int2[782*5120]
  const size_t off_rowstart = 0;
  const size_t off_rowlen   = 100000;
  const size_t off_tail     = 200000;
  const size_t off_stage    = 200784;              // *4B = 803136, 16B aligned
  int*  row_start = (int*)d_ws + off_rowstart;
  int*  row_len   = (int*)d_ws + off_rowlen;
  int*  tail      = (int*)d_ws + off_tail;
  int2* stage     = (int2*)((int*)d_ws + off_stage);

  k_init<<<(kNTotal * 16 + BS - 1) / BS, BS, 0, stream>>>(ue, ie, out, tail);
  k_split1<<<kP1Blocks, 256, 0, stream>>>(
      er, ec, ev, tail, stage,
      ke0[0], ke1[0], ke0[1], ke1[1], ke0[2], ke1[2]);
  k_split2<<<kNSB, 256, 0, stream>>>(tail, stage, row_start, row_len);

  for (int hop = 0; hop < kHops; ++hop) {
    const float* src = out + (size_t)hop * kD;
    float*       dst = out + (size_t)(hop + 1) * kD;
    k_spmm_csr<<<(kNTotal + 3) / 4, 256, 0, stream>>>(
        row_start, row_len, stage, src, dst, 1u << (17 + hop), km0[hop], km1[hop]);
  }
}

// Round 9
// 334.372 us; speedup vs baseline: 1.0157x; 1.0157x over previous
//
#include <hip/hip_runtime.h>
#include <cstdint>

namespace {
constexpr int kNUsers = 50000;
constexpr int kNTotal = 100000;        // N = users + items
constexpr int kD = 64;
constexpr int kHops = 3;
constexpr int kNnz = 3200000;
constexpr int kRowStride = (kHops + 1) * kD;     // 256 floats per node in embs
// packed edge word: col bits 0..16, keep bits 17..19, rowoff bits 20..26
constexpr uint32_t kColMask = (1u << 17) - 1u;
constexpr int kSBShift = 7;                      // 128 rows per super-bucket
constexpr int kSBRows = 1 << kSBShift;
constexpr int kNSB = (kNTotal + kSBRows - 1) / kSBRows;       // 782
constexpr int kSBCap = 5120;      // mean 4092, sigma 64 -> +16 sigma, fixed dataset
constexpr int kP1Batch = 16384;   // edges per split1 block -> chunk ~21 entries (~3 lines)
constexpr int kP1Blocks = (kNnz + kP1Batch - 1) / kP1Batch;   // 196
}

#define ROTL32(v, r) (((v) << (r)) | ((v) >> (32 - (r))))

// JAX threefry2x32, 20 rounds — matches jax/_src/prng.py exactly.
__host__ __device__ inline void tf2x32(uint32_t k0, uint32_t k1,
                                       uint32_t &x0, uint32_t &x1) {
  const uint32_t k2 = k0 ^ k1 ^ 0x1BD11BDAu;
  x0 += k0; x1 += k1;
#define TFR(r) { x0 += x1; x1 = ROTL32(x1, r); x1 ^= x0; }
  TFR(13) TFR(15) TFR(26) TFR(6)
  x0 += k1; x1 += k2 + 1u;
  TFR(17) TFR(29) TFR(16) TFR(24)
  x0 += k2; x1 += k0 + 2u;
  TFR(13) TFR(15) TFR(26) TFR(6)
  x0 += k0; x1 += k1 + 3u;
  TFR(17) TFR(29) TFR(16) TFR(24)
  x0 += k1; x1 += k2 + 4u;
  TFR(13) TFR(15) TFR(26) TFR(6)
  x0 += k2; x1 += k0 + 5u;
#undef TFR
}

// partitionable random_bits for 32-bit draws: counter (0, i), fold x0^x1
__device__ __forceinline__ uint32_t pbits(uint32_t k0, uint32_t k1, uint32_t i) {
  uint32_t x0 = 0u, x1 = i;
  tf2x32(k0, k1, x0, x1);
  return x0 ^ x1;
}

// bits -> U[0,1) exactly like jax.random.uniform (f32): (b>>9)|0x3f800000, -1.0
__device__ __forceinline__ float u01(uint32_t b) {
  return __uint_as_float((b >> 9) | 0x3f800000u) - 1.0f;
}

// embs[:,0,:] = concat(user, item). One thread per (node, float4). Zeros tail[].
__global__ void k_init(const float* __restrict__ ue, const float* __restrict__ ie,
                       float* __restrict__ out, int* __restrict__ tail) {
  int t = blockIdx.x * blockDim.x + threadIdx.x;
  if (t < kNSB) tail[t] = 0;
  if (t >= kNTotal * 16) return;
  int n = t >> 4, c = t & 15;
  float4 v = (n < kNUsers) ? reinterpret_cast<const float4*>(ue)[n * 16 + c]
                           : reinterpret_cast<const float4*>(ie)[(n - kNUsers) * 16 + c];
  reinterpret_cast<float4*>(out)[(size_t)n * (kRowStride / 4) + c] = v;
}

// ---------------- multisplit pass 1: block-aggregated bucket append ----------------
// 196 blocks x 16384 edges: mean chunk per (block,bucket) = 21 entries = 168 B
// (~3 full lines) -> minimal partial-line write amplification. Occupancy is low
// but round-8 proved this kernel is write-amp-bound, not latency-bound.
// er is read twice; the 2nd read hits L2 (64 KB/block slice). ec/ev nontemporal.
__global__ __launch_bounds__(256) void k_split1(
    const int* __restrict__ er, const int* __restrict__ ec,
    const float* __restrict__ ev, int* __restrict__ tail,
    int2* __restrict__ stage,
    uint32_t ke0_0, uint32_t ke1_0, uint32_t ke0_1, uint32_t ke1_1,
    uint32_t ke0_2, uint32_t ke1_2) {
  __shared__ int hist[kNSB];
  __shared__ int base[kNSB];
  const int t = threadIdx.x;
  const int e0 = blockIdx.x * kP1Batch;
  const int n = min(kP1Batch, kNnz - e0);
  for (int i = t; i < kNSB; i += 256) hist[i] = 0;
  __syncthreads();
#pragma unroll 4
  for (int i = t; i < n; i += 256)
    atomicAdd(&hist[(uint32_t)er[e0 + i] >> kSBShift], 1);
  __syncthreads();
  for (int i = t; i < kNSB; i += 256) {
    const int c = hist[i];
    base[i] = (c > 0) ? atomicAdd(&tail[i], c) : 0;
    hist[i] = 0;                     // reuse as cursor
  }
  __syncthreads();
#pragma unroll 2
  for (int i = t; i < n; i += 256) {
    const int e = e0 + i;
    const int r = er[e];             // L2-hot re-read
    const int b = (uint32_t)r >> kSBShift;
    const int pos = base[b] + atomicAdd(&hist[b], 1);
    if (pos < kSBCap) {              // 16-sigma guard; never triggers
      uint32_t x = (uint32_t)__builtin_nontemporal_load(ec + e);
      const float v = __builtin_nontemporal_load(ev + e);
      if (u01(pbits(ke0_0, ke1_0, (uint32_t)e)) >= 0.5f) x |= 1u << 17;
      if (u01(pbits(ke0_1, ke1_1, (uint32_t)e)) >= 0.5f) x |= 1u << 18;
      if (u01(pbits(ke0_2, ke1_2, (uint32_t)e)) >= 0.5f) x |= 1u << 19;
      x |= (uint32_t)(r & (kSBRows - 1)) << 20;
      stage[(size_t)b * kSBCap + pos] = make_int2((int)x, __float_as_int(v * 2.0f));
    }
  }
}

// ---------------- multisplit pass 2: per-bucket row sort (in place) ----------------
__global__ __launch_bounds__(256) void k_split2(
    const int* __restrict__ tail, int2* __restrict__ stage,
    int* __restrict__ row_start, int* __restrict__ row_len) {
  __shared__ int2 st[kSBCap];        // 40 KB
  __shared__ int lcnt[kSBRows], lsc[kSBRows], lcur[kSBRows];
  const int b = blockIdx.x;
  const int t = threadIdx.x;
  const int row0 = b << kSBShift;
  const int nrows = min(kSBRows, kNTotal - row0);
  const int n = min(tail[b], kSBCap);
  int2* reg = stage + (size_t)b * kSBCap;
  if (t < kSBRows) { lcnt[t] = 0; lcur[t] = 0; }
  for (int i = t; i < n; i += 256) st[i] = reg[i];
  __syncthreads();
  for (int i = t; i < n; i += 256)
    atomicAdd(&lcnt[((uint32_t)st[i].x >> 20) & (kSBRows - 1u)], 1);
  __syncthreads();
  if (t < kSBRows) lsc[t] = lcnt[t];
  __syncthreads();
  for (int off = 1; off < kSBRows; off <<= 1) {   // Hillis-Steele inclusive
    int add = (t >= off && t < kSBRows) ? lsc[t - off] : 0;
    __syncthreads();
    if (t < kSBRows) lsc[t] += add;
    __syncthreads();
  }
  if (t < nrows) {
    const int excl = lsc[t] - lcnt[t];
    row_start[row0 + t] = b * kSBCap + excl;
    row_len[row0 + t] = lcnt[t];
  }
  __syncthreads();
  for (int i = t; i < n; i += 256) {
    const int2 v = st[i];
    const int r = (int)(((uint32_t)v.x >> 20) & (kSBRows - 1u));
    const int pos = (lsc[r] - lcnt[r]) + atomicAdd(&lcur[r], 1);
    reg[pos] = v;
  }
}

// ---------------- fused SpMM: one wave per row ----------------
__global__ __launch_bounds__(256) void k_spmm_csr(
    const int* __restrict__ row_start, const int* __restrict__ row_len,
    const int2* __restrict__ csr,
    const float* __restrict__ src, float* __restrict__ dst,
    uint32_t hopbit, uint32_t km0, uint32_t km1) {
  __shared__ int2 stage[4][68];
  const int wave = threadIdx.x >> 6;
  const int lane = threadIdx.x & 63;
  const int r = __builtin_amdgcn_readfirstlane(blockIdx.x * 4 + wave);
  if (r >= kNTotal) return;
  const int start = row_start[r];
  const int end = start + row_len[r];
  float a0 = 0.f, a1 = 0.f, a2 = 0.f, a3 = 0.f;
  for (int base = start; base < end; base += 64) {
    const int n = min(64, end - base);
    bool keep = false;
    int2 cv = make_int2(0, 0);
    if (lane < n) {
      cv = csr[base + lane];
      keep = ((uint32_t)cv.x & hopbit) != 0u;
    }
    const uint64_t m = __ballot(keep);
    const int k = __popcll(m);
    if (keep) {
      const int slot = __popcll(m & ((1ull << lane) - 1ull));
      stage[wave][slot] = make_int2((int)((uint32_t)cv.x & kColMask), cv.y);
    }
    if (lane < 3) stage[wave][k + lane] = make_int2(0, 0);  // zero-pad for unroll tail
    for (int j = 0; j < k; j += 4) {
      const int2 e0 = stage[wave][j];
      const int2 e1 = stage[wave][j + 1];
      const int2 e2 = stage[wave][j + 2];
      const int2 e3 = stage[wave][j + 3];
      a0 += __int_as_float(e0.y) * src[(size_t)e0.x * kRowStride + lane];
      a1 += __int_as_float(e1.y) * src[(size_t)e1.x * kRowStride + lane];
      a2 += __int_as_float(e2.y) * src[(size_t)e2.x * kRowStride + lane];
      a3 += __int_as_float(e3.y) * src[(size_t)e3.x * kRowStride + lane];
    }
  }
  const float acc = (a0 + a1) + (a2 + a3);
  const float u = u01(pbits(km0, km1, (uint32_t)(r * 64 + lane)));
  dst[(size_t)r * kRowStride + lane] = (u < 0.9f) ? acc * (float)(1.0 / 0.9) : 0.0f;
}

extern "C" void kernel_launch(void* const* d_in, const int* in_sizes, int n_in,
                              void* d_out, int out_size, void* d_ws, size_t ws_size,
                              hipStream_t stream) {
  const float* ue = (const float*)d_in[0];
  const float* ie = (const float*)d_in[1];
  const float* ev = (const float*)d_in[2];
  const int*   er = (const int*)d_in[3];
  const int*   ec = (const int*)d_in[4];
  float* out = (float*)d_out;

  // keys: base = key(42) = (0,42); per hop fold_in, then partitionable split:
  // keys[j] = threefry(folded_key, (0, j)).
  uint32_t ke0[kHops], ke1[kHops], km0[kHops], km1[kHops];
  for (int hop = 0; hop < kHops; ++hop) {
    uint32_t f0 = 0u, f1 = (uint32_t)hop;
    tf2x32(0u, 42u, f0, f1);
    uint32_t e0 = 0u, e1 = 0u;
    tf2x32(f0, f1, e0, e1);
    uint32_t m0 = 0u, m1 = 1u;
    tf2x32(f0, f1, m0, m1);
    ke0[hop] = e0; ke1[hop] = e1;
    km0[hop] = m0; km1[hop] = m1;
  }

  const int BS = 256;

  // ws layout (int units):
  // row_start[100000] | row_len[100000] | tail[782] | pad | stage int2[782*5120]
  const size_t off_rowstart = 0;
  const size_t off_rowlen   = 100000;
  const size_t off_tail     = 200000;
  const size_t off_stage    = 200784;              // *4B = 803136, 16B aligned
  int*  row_start = (int*)d_ws + off_rowstart;
  int*  row_len   = (int*)d_ws + off_rowlen;
  int*  tail      = (int*)d_ws + off_tail;
  int2* stage     = (int2*)((int*)d_ws + off_stage);

  k_init<<<(kNTotal * 16 + BS - 1) / BS, BS, 0, stream>>>(ue, ie, out, tail);
  k_split1<<<kP1Blocks, 256, 0, stream>>>(
      er, ec, ev, tail, stage,
      ke0[0], ke1[0], ke0[1], ke1[1], ke0[2], ke1[2]);
  k_split2<<<kNSB, 256, 0, stream>>>(tail, stage, row_start, row_len);

  for (int hop = 0; hop < kHops; ++hop) {
    const float* src = out + (size_t)hop * kD;
    float*       dst = out + (size_t)(hop + 1) * kD;
    k_spmm_csr<<<(kNTotal + 3) / 4, 256, 0, stream>>>(
        row_start, row_len, stage, src, dst, 1u << (17 + hop), km0[hop], km1[hop]);
  }
}

// Round 10
// 292.064 us; speedup vs baseline: 1.1628x; 1.1449x over previous
//
#include <hip/hip_runtime.h>
#include <cstdint>

namespace {
constexpr int kNUsers = 50000;
constexpr int kNTotal = 100000;        // N = users + items
constexpr int kD = 64;
constexpr int kHops = 3;
constexpr int kNnz = 3200000;
constexpr int kRowStride = (kHops + 1) * kD;     // 256 floats per node in embs
// packed edge word: col bits 0..16, keep bits 17..19, rowoff bits 20..26
constexpr uint32_t kColMask = (1u << 17) - 1u;
constexpr int kSBShift = 7;                      // 128 rows per super-bucket
constexpr int kSBRows = 1 << kSBShift;
constexpr int kNSB = (kNTotal + kSBRows - 1) / kSBRows;       // 782
constexpr int kSBCap = 5120;      // mean 4092, sigma 64 -> +16 sigma, fixed dataset
constexpr int kP1Batch = 16384;   // chunk ~21 entries (~3 lines) -> low write amp
constexpr int kP1Blocks = (kNnz + kP1Batch - 1) / kP1Batch;   // 196
constexpr int kP1Threads = 1024;  // 16 waves/block -> latency hiding (R9 fix)
constexpr int kEPT = kP1Batch / kP1Threads;      // 16 edges per thread
}

#define ROTL32(v, r) (((v) << (r)) | ((v) >> (32 - (r))))

// JAX threefry2x32, 20 rounds — matches jax/_src/prng.py exactly.
__host__ __device__ inline void tf2x32(uint32_t k0, uint32_t k1,
                                       uint32_t &x0, uint32_t &x1) {
  const uint32_t k2 = k0 ^ k1 ^ 0x1BD11BDAu;
  x0 += k0; x1 += k1;
#define TFR(r) { x0 += x1; x1 = ROTL32(x1, r); x1 ^= x0; }
  TFR(13) TFR(15) TFR(26) TFR(6)
  x0 += k1; x1 += k2 + 1u;
  TFR(17) TFR(29) TFR(16) TFR(24)
  x0 += k2; x1 += k0 + 2u;
  TFR(13) TFR(15) TFR(26) TFR(6)
  x0 += k0; x1 += k1 + 3u;
  TFR(17) TFR(29) TFR(16) TFR(24)
  x0 += k1; x1 += k2 + 4u;
  TFR(13) TFR(15) TFR(26) TFR(6)
  x0 += k2; x1 += k0 + 5u;
#undef TFR
}

// partitionable random_bits for 32-bit draws: counter (0, i), fold x0^x1
__device__ __forceinline__ uint32_t pbits(uint32_t k0, uint32_t k1, uint32_t i) {
  uint32_t x0 = 0u, x1 = i;
  tf2x32(k0, k1, x0, x1);
  return x0 ^ x1;
}

// bits -> U[0,1) exactly like jax.random.uniform (f32): (b>>9)|0x3f800000, -1.0
__device__ __forceinline__ float u01(uint32_t b) {
  return __uint_as_float((b >> 9) | 0x3f800000u) - 1.0f;
}

// embs[:,0,:] = concat(user, item). One thread per (node, float4). Zeros tail[].
__global__ void k_init(const float* __restrict__ ue, const float* __restrict__ ie,
                       float* __restrict__ out, int* __restrict__ tail) {
  int t = blockIdx.x * blockDim.x + threadIdx.x;
  if (t < kNSB) tail[t] = 0;
  if (t >= kNTotal * 16) return;
  int n = t >> 4, c = t & 15;
  float4 v = (n < kNUsers) ? reinterpret_cast<const float4*>(ue)[n * 16 + c]
                           : reinterpret_cast<const float4*>(ie)[(n - kNUsers) * 16 + c];
  reinterpret_cast<float4*>(out)[(size_t)n * (kRowStride / 4) + c] = v;
}

// ---------------- multisplit pass 1: block-aggregated bucket append ----------------
// 196 blocks x 16384 edges x 1024 threads. Big batch keeps chunk per
// (block,bucket) ~21 entries (~3 full lines, W~75MB proven R9); 16 waves/block
// restores the TLP that R9's 4-wave config lacked. er register-cached (16/thread,
// full unroll = static indices). ec/ev nontemporal (read once).
__global__ __launch_bounds__(1024) void k_split1(
    const int* __restrict__ er, const int* __restrict__ ec,
    const float* __restrict__ ev, int* __restrict__ tail,
    int2* __restrict__ stage,
    uint32_t ke0_0, uint32_t ke1_0, uint32_t ke0_1, uint32_t ke1_1,
    uint32_t ke0_2, uint32_t ke1_2) {
  __shared__ int hist[kNSB];
  __shared__ int base[kNSB];
  const int t = threadIdx.x;
  const int e0 = blockIdx.x * kP1Batch;
  const int n = min(kP1Batch, kNnz - e0);
  for (int i = t; i < kNSB; i += kP1Threads) hist[i] = 0;
  __syncthreads();
  int rr[kEPT];
#pragma unroll
  for (int j = 0; j < kEPT; ++j) {
    const int i = j * kP1Threads + t;
    rr[j] = (i < n) ? __builtin_nontemporal_load(er + e0 + i) : -1;
    if (rr[j] >= 0) atomicAdd(&hist[(uint32_t)rr[j] >> kSBShift], 1);
  }
  __syncthreads();
  for (int i = t; i < kNSB; i += kP1Threads) {
    const int c = hist[i];
    base[i] = (c > 0) ? atomicAdd(&tail[i], c) : 0;
    hist[i] = 0;                     // reuse as cursor
  }
  __syncthreads();
#pragma unroll
  for (int j = 0; j < kEPT; ++j) {
    if (rr[j] < 0) continue;
    const int e = e0 + j * kP1Threads + t;
    const int b = (uint32_t)rr[j] >> kSBShift;
    const int pos = base[b] + atomicAdd(&hist[b], 1);
    if (pos < kSBCap) {              // 16-sigma guard; never triggers
      uint32_t x = (uint32_t)__builtin_nontemporal_load(ec + e);
      const float v = __builtin_nontemporal_load(ev + e);
      if (u01(pbits(ke0_0, ke1_0, (uint32_t)e)) >= 0.5f) x |= 1u << 17;
      if (u01(pbits(ke0_1, ke1_1, (uint32_t)e)) >= 0.5f) x |= 1u << 18;
      if (u01(pbits(ke0_2, ke1_2, (uint32_t)e)) >= 0.5f) x |= 1u << 19;
      x |= (uint32_t)(rr[j] & (kSBRows - 1)) << 20;
      stage[(size_t)b * kSBCap + pos] = make_int2((int)x, __float_as_int(v * 2.0f));
    }
  }
}

// ---------------- multisplit pass 2: per-bucket row sort (in place) ----------------
__global__ __launch_bounds__(256) void k_split2(
    const int* __restrict__ tail, int2* __restrict__ stage,
    int* __restrict__ row_start, int* __restrict__ row_len) {
  __shared__ int2 st[kSBCap];        // 40 KB
  __shared__ int lcnt[kSBRows], lsc[kSBRows], lcur[kSBRows];
  const int b = blockIdx.x;
  const int t = threadIdx.x;
  const int row0 = b << kSBShift;
  const int nrows = min(kSBRows, kNTotal - row0);
  const int n = min(tail[b], kSBCap);
  int2* reg = stage + (size_t)b * kSBCap;
  if (t < kSBRows) { lcnt[t] = 0; lcur[t] = 0; }
  for (int i = t; i < n; i += 256) st[i] = reg[i];
  __syncthreads();
  for (int i = t; i < n; i += 256)
    atomicAdd(&lcnt[((uint32_t)st[i].x >> 20) & (kSBRows - 1u)], 1);
  __syncthreads();
  if (t < kSBRows) lsc[t] = lcnt[t];
  __syncthreads();
  for (int off = 1; off < kSBRows; off <<= 1) {   // Hillis-Steele inclusive
    int add = (t >= off && t < kSBRows) ? lsc[t - off] : 0;
    __syncthreads();
    if (t < kSBRows) lsc[t] += add;
    __syncthreads();
  }
  if (t < nrows) {
    const int excl = lsc[t] - lcnt[t];
    row_start[row0 + t] = b * kSBCap + excl;
    row_len[row0 + t] = lcnt[t];
  }
  __syncthreads();
  for (int i = t; i < n; i += 256) {
    const int2 v = st[i];
    const int r = (int)(((uint32_t)v.x >> 20) & (kSBRows - 1u));
    const int pos = (lsc[r] - lcnt[r]) + atomicAdd(&lcur[r], 1);
    reg[pos] = v;
  }
}

// ---------------- fused SpMM: one wave per row ----------------
__global__ __launch_bounds__(256) void k_spmm_csr(
    const int* __restrict__ row_start, const int* __restrict__ row_len,
    const int2* __restrict__ csr,
    const float* __restrict__ src, float* __restrict__ dst,
    uint32_t hopbit, uint32_t km0, uint32_t km1) {
  __shared__ int2 stage[4][68];
  const int wave = threadIdx.x >> 6;
  const int lane = threadIdx.x & 63;
  const int r = __builtin_amdgcn_readfirstlane(blockIdx.x * 4 + wave);
  if (r >= kNTotal) return;
  const int start = row_start[r];
  const int end = start + row_len[r];
  float a0 = 0.f, a1 = 0.f, a2 = 0.f, a3 = 0.f;
  for (int base = start; base < end; base += 64) {
    const int n = min(64, end - base);
    bool keep = false;
    int2 cv = make_int2(0, 0);
    if (lane < n) {
      cv = csr[base + lane];
      keep = ((uint32_t)cv.x & hopbit) != 0u;
    }
    const uint64_t m = __ballot(keep);
    const int k = __popcll(m);
    if (keep) {
      const int slot = __popcll(m & ((1ull << lane) - 1ull));
      stage[wave][slot] = make_int2((int)((uint32_t)cv.x & kColMask), cv.y);
    }
    if (lane < 3) stage[wave][k + lane] = make_int2(0, 0);  // zero-pad for unroll tail
    for (int j = 0; j < k; j += 4) {
      const int2 e0 = stage[wave][j];
      const int2 e1 = stage[wave][j + 1];
      const int2 e2 = stage[wave][j + 2];
      const int2 e3 = stage[wave][j + 3];
      a0 += __int_as_float(e0.y) * src[(size_t)e0.x * kRowStride + lane];
      a1 += __int_as_float(e1.y) * src[(size_t)e1.x * kRowStride + lane];
      a2 += __int_as_float(e2.y) * src[(size_t)e2.x * kRowStride + lane];
      a3 += __int_as_float(e3.y) * src[(size_t)e3.x * kRowStride + lane];
    }
  }
  const float acc = (a0 + a1) + (a2 + a3);
  const float u = u01(pbits(km0, km1, (uint32_t)(r * 64 + lane)));
  dst[(size_t)r * kRowStride + lane] = (u < 0.9f) ? acc * (float)(1.0 / 0.9) : 0.0f;
}

extern "C" void kernel_launch(void* const* d_in, const int* in_sizes, int n_in,
                              void* d_out, int out_size, void* d_ws, size_t ws_size,
                              hipStream_t stream) {
  const float* ue = (const float*)d_in[0];
  const float* ie = (const float*)d_in[1];
  const float* ev = (const float*)d_in[2];
  const int*   er = (const int*)d_in[3];
  const int*   ec = (const int*)d_in[4];
  float* out = (float*)d_out;

  // keys: base = key(42) = (0,42); per hop fold_in, then partitionable split:
  // keys[j] = threefry(folded_key, (0, j)).
  uint32_t ke0[kHops], ke1[kHops], km0[kHops], km1[kHops];
  for (int hop = 0; hop < kHops; ++hop) {
    uint32_t f0 = 0u, f1 = (uint32_t)hop;
    tf2x32(0u, 42u, f0, f1);
    uint32_t e0 = 0u, e1 = 0u;
    tf2x32(f0, f1, e0, e1);
    uint32_t m0 = 0u, m1 = 1u;
    tf2x32(f0, f1, m0, m1);
    ke0[hop] = e0; ke1[hop] = e1;
    km0[hop] = m0; km1[hop] = m1;
  }

  const int BS = 256;

  // ws layout (int units):
  // row_start[100000] | row_len[100000] | tail[782] | pad | stage int2[782*5120]
  const size_t off_rowstart = 0;
  const size_t off_rowlen   = 100000;
  const size_t off_tail     = 200000;
  const size_t off_stage    = 200784;              // *4B = 803136, 16B aligned
  int*  row_start = (int*)d_ws + off_rowstart;
  int*  row_len   = (int*)d_ws + off_rowlen;
  int*  tail      = (int*)d_ws + off_tail;
  int2* stage     = (int2*)((int*)d_ws + off_stage);

  k_init<<<(kNTotal * 16 + BS - 1) / BS, BS, 0, stream>>>(ue, ie, out, tail);
  k_split1<<<kP1Blocks, kP1Threads, 0, stream>>>(
      er, ec, ev, tail, stage,
      ke0[0], ke1[0], ke0[1], ke1[1], ke0[2], ke1[2]);
  k_split2<<<kNSB, 256, 0, stream>>>(tail, stage, row_start, row_len);

  for (int hop = 0; hop < kHops; ++hop) {
    const float* src = out + (size_t)hop * kD;
    float*       dst = out + (size_t)(hop + 1) * kD;
    k_spmm_csr<<<(kNTotal + 3) / 4, 256, 0, stream>>>(
        row_start, row_len, stage, src, dst, 1u << (17 + hop), km0[hop], km1[hop]);
  }
}